// Round 12
// baseline (972.865 us; speedup 1.0000x reference)
//
#include <hip/hip_runtime.h>
#include <hip/hip_fp8.h>

typedef unsigned short u16;
typedef unsigned char u8;
typedef __attribute__((ext_vector_type(8))) __bf16 bfrag;
typedef long long f8frag;
typedef __attribute__((ext_vector_type(4))) float f32x4;

static __device__ __forceinline__ f32x4 MFMA(bfrag a, bfrag b, f32x4 c) {
  return __builtin_amdgcn_mfma_f32_16x16x32_bf16(a, b, c, 0, 0, 0);
}
static __device__ __forceinline__ f32x4 MFMA8(f8frag a, f8frag b, f32x4 c) {
  return __builtin_amdgcn_mfma_f32_16x16x32_fp8_fp8(a, b, c, 0, 0, 0);
}

// float -> bf16 (RNE)
static __device__ __forceinline__ u16 f2b(float f) {
  union { float f; unsigned u; } v; v.f = f;
  unsigned r = (v.u + 0x7fffu + ((v.u >> 16) & 1u)) >> 16;
  return (u16)r;
}
// float -> fp8 e4m3 (OCP)
static __device__ __forceinline__ u8 f2e4m3(float f) {
  return __hip_fp8_e4m3(f).__x;
}
static __device__ __forceinline__ float ssig(float x) { return 1.f / (1.f + __expf(-x)); }
static __device__ __forceinline__ float stanh(float x) { return 1.f - 2.f / (__expf(2.f * x) + 1.f); }

// ---------------------------------------------------------------------------
// prep. Decode gate-retile: MFMA col n = g16*64 + gate*16 + m15 <-> source
// row gate*256 + g16*16 + m15.
// Case 15: decode weights fp8 LANE-SWIZZLED CONTIGUOUS stream layout:
//   WsS[(((g16*4+gate)*8+kt)*64+lane)*8+j]
//     = fp8( Wcomb[gate*256 + g16*16 + (lane&15)][kt*32 + (lane>>4)*8 + j] )
// (one contiguous 512 B block per (gate,kt) fragment -> single-segment load;
//  this was the R11 2.4x win). Cases 12/13: pred weights, same swizzle.
// Case 16: bH123 = concat(bh1,bc1,bx1) for the fused N=1536 head-1 GEMM.
// ---------------------------------------------------------------------------
struct PrepArgs {
  const float *x, *W1, *W2, *W3, *Wh1, *Wc1, *Wx1, *Wh2, *Wc2, *Wx2;
  const float *rWih, *rWhh, *rbih, *rbhh, *pWih, *pWhh, *pbih, *pbhh;
  const float *bh1, *bc1, *bx1;
  u16 *Xbf, *W1b, *W2b, *W3b, *Wh1b, *Wc1b, *Wx1b, *Wh2b, *Wc2b, *Wx2b;
  u16 *WcatR;
  u8 *WsS, *pWsS, *pWhhS;
  float *rbR, *pbR, *bH123;
};

__global__ __launch_bounds__(256) void prep(PrepArgs p) {
  const int tid0 = blockIdx.x * 256 + threadIdx.x;
  const int stride = gridDim.x * 256;
  switch (blockIdx.y) {
    case 0: for (int i = tid0; i < 131072; i += stride) p.Xbf[i] = f2b(p.x[i]); break;
    case 1: for (int i = tid0; i < 65536;  i += stride) p.W1b[i] = f2b(p.W1[i]); break;
    case 2: for (int i = tid0; i < 262144; i += stride) p.W2b[i] = f2b(p.W2[i]); break;
    case 3: for (int i = tid0; i < 262144; i += stride) p.W3b[i] = f2b(p.W3[i]); break;
    case 4: for (int i = tid0; i < 262144; i += stride) p.Wh1b[i] = f2b(p.Wh1[i]); break;
    case 5: for (int i = tid0; i < 262144; i += stride) p.Wc1b[i] = f2b(p.Wc1[i]); break;
    case 6: for (int i = tid0; i < 262144; i += stride) p.Wx1b[i] = f2b(p.Wx1[i]); break;
    case 7: for (int i = tid0; i < 131072; i += stride) p.Wh2b[i] = f2b(p.Wh2[i]); break;
    case 8: for (int i = tid0; i < 131072; i += stride) p.Wc2b[i] = f2b(p.Wc2[i]); break;
    case 9: for (int i = tid0; i < 131072; i += stride) p.Wx2b[i] = f2b(p.Wx2[i]); break;
    case 10: // step-0 concat weights (bf16, gate-retiled)
      for (int i = tid0; i < 262144; i += stride) {
        int n = i >> 8, k = i & 255;
        int srow = (((n >> 4) & 3) << 8) + ((n >> 6) << 4) + (n & 15);
        p.WcatR[n * 512 + k] = f2b(p.rWih[srow * 256 + k]);
        p.WcatR[n * 512 + 256 + k] = f2b(p.rWhh[srow * 256 + k]);
      }
      break;
    case 11:
      for (int i = tid0; i < 1024; i += stride) {
        int srow = (((i >> 4) & 3) << 8) + ((i >> 6) << 4) + (i & 15);
        p.rbR[i] = p.rbih[srow] + p.rbhh[srow];
      }
      break;
    case 12: // pred x-weights fp8, swizzled-contiguous
      for (int i = tid0; i < 32768; i += stride) {
        int j = i & 7, lane = (i >> 3) & 63, kt = (i >> 9) & 7, w = i >> 12;
        int n = w * 16 + (lane & 15);
        int srow = ((n & 3) << 5) + (n >> 2);
        int k = kt * 32 + ((lane >> 4) & 3) * 8 + j;
        p.pWsS[i] = f2e4m3(p.pWih[srow * 256 + k]);
      }
      break;
    case 13: // pred h-weights fp8, swizzled-contiguous
      for (int i = tid0; i < 4096; i += stride) {
        int j = i & 7, lane = (i >> 3) & 63, w = i >> 9;
        int n = w * 16 + (lane & 15);
        int srow = ((n & 3) << 5) + (n >> 2);
        int k = ((lane >> 4) & 3) * 8 + j;
        p.pWhhS[i] = f2e4m3(p.pWhh[srow * 32 + k]);
      }
      break;
    case 14:
      for (int i = tid0; i < 128; i += stride) {
        int srow = ((i & 3) << 5) + (i >> 2);
        p.pbR[i] = p.pbih[srow] + p.pbhh[srow];
      }
      break;
    case 15: // decode combined weights fp8, swizzled-contiguous stream layout
      for (int i = tid0; i < 262144; i += stride) {
        int j = i & 7, lane = (i >> 3) & 63, kt = (i >> 9) & 7;
        int gate = (i >> 12) & 3, g16 = i >> 14;
        int srow = gate * 256 + g16 * 16 + (lane & 15);
        int k = kt * 32 + ((lane >> 4) & 3) * 8 + j;
        p.WsS[i] = f2e4m3(p.rWih[srow * 256 + k] + p.rWhh[srow * 256 + k]);
      }
      break;
    case 16: // concat head-1 biases
      for (int i = tid0; i < 1536; i += stride)
        p.bH123[i] = (i < 512) ? p.bh1[i] : (i < 1024) ? p.bc1[i - 512] : p.bx1[i - 1024];
      break;
  }
}

// ---------------------------------------------------------------------------
// gemm_act: Y[1024,N] = act(X[1024,K] @ W[N,K]^T + bias), bf16 in, fp32 acc.
// lda = row stride of X (supports strided slices of the fused THCX buffer).
// ---------------------------------------------------------------------------
__global__ __launch_bounds__(256) void gemm_act(
    const u16* __restrict__ X, const u16* __restrict__ W,
    const float* __restrict__ bias,
    u16* __restrict__ Yb, float* __restrict__ Yf,
    int K, int lda, int ldo, int coloff, int leaky) {
  const int rt = blockIdx.x, ct = blockIdx.y;
  const int lane = threadIdx.x & 63, wave = threadIdx.x >> 6;
  const int m15 = lane & 15, q = lane >> 4, kq = q * 8;
  const int row = rt * 64 + wave * 16 + m15;
  f32x4 acc[4] = {};
  const u16* xp = X + (size_t)row * lda + kq;
  for (int k0 = 0; k0 < K; k0 += 32) {
    bfrag a = *(const bfrag*)(xp + k0);
#pragma unroll
    for (int nt = 0; nt < 4; nt++) {
      const u16* wp = W + (size_t)(ct * 64 + nt * 16 + m15) * K + k0 + kq;
      acc[nt] = MFMA(a, *(const bfrag*)wp, acc[nt]);
    }
  }
#pragma unroll
  for (int nt = 0; nt < 4; nt++) {
    int col = ct * 64 + nt * 16 + m15;
    float bv = bias[col];
#pragma unroll
    for (int r = 0; r < 4; r++) {
      int orow = rt * 64 + wave * 16 + q * 4 + r;
      float v = acc[nt][r] + bv;
      if (leaky) v = v >= 0.f ? v : 0.2f * v;
      if (Yb) Yb[(size_t)orow * ldo + coloff + col] = f2b(v);
      else    Yf[(size_t)orow * ldo + coloff + col] = v;
    }
  }
}

// ---------------------------------------------------------------------------
// decode_step: step 0 only (K=512 concat input, bf16), gate-retiled columns.
// ---------------------------------------------------------------------------
__global__ __launch_bounds__(256) void decode_step(
    const u16* __restrict__ A, const u16* __restrict__ W,
    const float* __restrict__ rb,
    float* __restrict__ C, u16* __restrict__ Hout, int K) {
  __shared__ float g[64][128];
  const int rt = blockIdx.x, cg = blockIdx.y;
  const int lane = threadIdx.x & 63, wave = threadIdx.x >> 6;
  const int m15 = lane & 15, q = lane >> 4, kq = q * 8;
  const int row = rt * 64 + wave * 16 + m15;
  f32x4 acc[8] = {};
  const u16* ap = A + (size_t)row * K + kq;
  for (int k0 = 0; k0 < K; k0 += 32) {
    bfrag a = *(const bfrag*)(ap + k0);
#pragma unroll
    for (int nt = 0; nt < 8; nt++) {
      const u16* wp = W + (size_t)(cg * 128 + nt * 16 + m15) * K + k0 + kq;
      acc[nt] = MFMA(a, *(const bfrag*)wp, acc[nt]);
    }
  }
#pragma unroll
  for (int nt = 0; nt < 8; nt++)
#pragma unroll
    for (int r = 0; r < 4; r++)
      g[wave * 16 + q * 4 + r][nt * 16 + m15] = acc[nt][r];
  __syncthreads();
  for (int t = threadIdx.x; t < 2048; t += 256) {
    int rl = t >> 5, hc = t & 31;
    int grow = rt * 64 + rl, gcol = cg * 32 + hc;
    int base = ((hc >> 4) << 6) + (hc & 15);
    float gi = g[rl][base +  0] + rb[cg * 128 + base +  0];
    float gf = g[rl][base + 16] + rb[cg * 128 + base + 16];
    float gg = g[rl][base + 32] + rb[cg * 128 + base + 32];
    float go = g[rl][base + 48] + rb[cg * 128 + base + 48];
    size_t ci = (size_t)grow * 256 + gcol;
    float c = C[ci];
    float cn = ssig(gf) * c + ssig(gi) * stanh(gg);
    float hn = ssig(go) * stanh(cn);
    C[ci] = cn;
    Hout[ci] = f2b(hn);
  }
}

// ---------------------------------------------------------------------------
// decode_pred v7 (3-stage pipeline): 64 blocks x 1024 thr, 16 rows/block.
// R11's batched-prefetch cut the step to ~9.2K cyc; the remaining serial
// tail was phase2 (pred+softmax on 8 waves, other 8 idle). Now ONE phase,
// ONE barrier: iteration s runs concurrently
//   decode(s)      on all 16 waves      (1<=s<=127)
//   pred(s-1)      extra on waves 0..7  (s>=1)
//   softmax(s-2)   extra on waves 8..15 (s>=2)
// All cross-stage edges go through depth-2 ping-pong buffers and cross
// exactly one barrier (hbuf8: dec(s)w -> dec(s+1)/pred(s)r; hp8: pred(t)w
// -> pred(t+1)r; ys: pred(t)w -> softmax(t)r, overwritten by pred(t+2)).
// ---------------------------------------------------------------------------
__global__ __launch_bounds__(1024, 4) void decode_pred(
    const u8* __restrict__ WsS,     // [262144] swizzled fp8 decode weights
    const float* __restrict__ rb,   // rbR [1024]
    const float* __restrict__ C0,   // CB  [1024][256] (c after step 0)
    const u16* __restrict__ H0,     // h_0 [1024][256] bf16
    const u8* __restrict__ pWsS,    // [32768] swizzled fp8 pred x-weights
    const u8* __restrict__ pWhhS,   // [4096] swizzled fp8 pred h-weights
    const float* __restrict__ pb,   // pbR [128]
    float* __restrict__ out) {      // [1024][128][32]
  __shared__ u8 hbuf8[2][16][272];     // 8.5 KB fp8 h ping-pong
  __shared__ float gbuf[8][16][20];    // 10 KB pred transpose
  __shared__ u8 hp8[2][16][40];        // 1.25 KB pred hidden
  __shared__ float ys[2][16][36];      // 4.5 KB pred y double-buffer
  const int tid = threadIdx.x;
  const int w = tid >> 6, lane = tid & 63;
  const int m15 = lane & 15, q = lane >> 4;
  const int rowg = blockIdx.x * 16;
  const int hc = w * 16 + m15;

  // h_0 -> fp8
  {
    int r = tid >> 6, c = (tid & 63) * 4;
    const u16* src = H0 + (size_t)(rowg + r) * 256 + c;
    u8 b4[4];
#pragma unroll
    for (int j = 0; j < 4; j++) {
      union { float f; unsigned u; } v; v.u = (unsigned)src[j] << 16;
      b4[j] = f2e4m3(v.f);
    }
    *(unsigned*)(&hbuf8[0][r][c]) =
        (unsigned)b4[0] | ((unsigned)b4[1] << 8) | ((unsigned)b4[2] << 16) | ((unsigned)b4[3] << 24);
  }
  for (int i = tid; i < 2 * 16 * 40; i += 1024) (&hp8[0][0][0])[i] = 0;

  // decode per-lane state
  float cst[4];
#pragma unroll
  for (int r = 0; r < 4; r++)
    cst[r] = C0[(size_t)(rowg + q * 4 + r) * 256 + hc];
  const float rbv0 = rb[w * 64 +  0 + m15], rbv1 = rb[w * 64 + 16 + m15];
  const float rbv2 = rb[w * 64 + 32 + m15], rbv3 = rb[w * 64 + 48 + m15];
  const u8* wsb = WsS + (size_t)w * 16384 + lane * 8;   // wave's swizzled base

  // pred constants (waves 0..7)
  const int hloc = lane >> 4, prow = lane & 15;
  const int pcol = w * 4 + hloc;
  const int pc = (w < 8) ? pcol : 0;
  const float pb0 = pb[pc * 4 + 0], pb1 = pb[pc * 4 + 1];
  const float pb2 = pb[pc * 4 + 2], pb3 = pb[pc * 4 + 3];
  const u8* pwsb = pWsS + (size_t)(w & 7) * 4096 + lane * 8;
  const u8* pwhb = pWhhS + (size_t)(w & 7) * 512 + lane * 8;
  float cp = 0.f;

  for (int s = 0; s <= 128; s++) {
    // ---------- stage 1: decode(s), all 16 waves ----------
    if (s >= 1 && s <= 127) {
      const u8* h8 = &hbuf8[(s - 1) & 1][0][0];
      f8frag Wv0[8], Wv1[8], Wv2[8], Wv3[8];
#pragma unroll
      for (int kt = 0; kt < 8; kt++) {
        Wv0[kt] = *(const f8frag*)(wsb + kt * 512);            // gate i
        Wv1[kt] = *(const f8frag*)(wsb + 4096 + kt * 512);     // gate f
        Wv2[kt] = *(const f8frag*)(wsb + 8192 + kt * 512);     // gate g
        Wv3[kt] = *(const f8frag*)(wsb + 12288 + kt * 512);    // gate o
      }
      f8frag a8v[8];
#pragma unroll
      for (int kt = 0; kt < 8; kt++)
        a8v[kt] = *(const f8frag*)(h8 + m15 * 272 + kt * 32 + q * 8);
      f32x4 ai = {}, af_ = {}, ag = {}, ao = {};
#pragma unroll
      for (int kt = 0; kt < 8; kt++) {
        ai  = MFMA8(a8v[kt], Wv0[kt], ai);
        af_ = MFMA8(a8v[kt], Wv1[kt], af_);
        ag  = MFMA8(a8v[kt], Wv2[kt], ag);
        ao  = MFMA8(a8v[kt], Wv3[kt], ao);
      }
      u8* hw8 = &hbuf8[s & 1][0][0];
#pragma unroll
      for (int r = 0; r < 4; r++) {
        float gi = ai[r] + rbv0, gf = af_[r] + rbv1;
        float gg = ag[r] + rbv2, go = ao[r] + rbv3;
        float cn = ssig(gf) * cst[r] + ssig(gi) * stanh(gg);
        float hn = ssig(go) * stanh(cn);
        cst[r] = cn;
        hw8[(q * 4 + r) * 272 + hc] = f2e4m3(hn);
      }
    }
    // ---------- stage 2: pred(s-1), waves 0..7 ----------
    if (w < 8 && s >= 1) {
      const int t = s - 1;
      const u8* xr8 = &hbuf8[t & 1][0][0];
      f8frag pbv[8], pav[8];
#pragma unroll
      for (int kt = 0; kt < 8; kt++) pbv[kt] = *(const f8frag*)(pwsb + kt * 512);
      f8frag phw = *(const f8frag*)pwhb;
#pragma unroll
      for (int kt = 0; kt < 8; kt++)
        pav[kt] = *(const f8frag*)(xr8 + m15 * 272 + kt * 32 + q * 8);
      f8frag pah = *(const f8frag*)(&hp8[t & 1][m15][q * 8]);
      f32x4 pacc = {};
#pragma unroll
      for (int kt = 0; kt < 8; kt++) pacc = MFMA8(pav[kt], pbv[kt], pacc);
      pacc = MFMA8(pah, phw, pacc);
      *(f32x4*)&gbuf[w][m15][q * 4] = pacc;  // per-wave transpose, in-order DS
      float g0 = gbuf[w][hloc * 4 + 0][prow] + pb0;
      float g1 = gbuf[w][hloc * 4 + 1][prow] + pb1;
      float g2 = gbuf[w][hloc * 4 + 2][prow] + pb2;
      float g3 = gbuf[w][hloc * 4 + 3][prow] + pb3;
      float cn = ssig(g1) * cp + ssig(g0) * stanh(g2);
      float hn_p = ssig(g3) * stanh(cn);
      cp = cn;
      hp8[(t + 1) & 1][prow][pcol] = f2e4m3(hn_p);
      ys[t & 1][prow][pcol] = hn_p;
    }
    // ---------- stage 3: softmax+out(s-2), waves 8..15 ----------
    if (w >= 8 && s >= 2) {
      const int u = s - 2;
      int row_ = (tid - 512) >> 5, j = tid & 31;
      float yv = ys[u & 1][row_][j];
      float m = (j < 31) ? yv : -1e30f;
#pragma unroll
      for (int off = 16; off; off >>= 1) m = fmaxf(m, __shfl_xor(m, off, 32));
      float es = (j < 31) ? __expf(yv - m) : 0.f;
      float tot = es;
#pragma unroll
      for (int off = 16; off; off >>= 1) tot += __shfl_xor(tot, off, 32);
      float outv = (j < 31) ? es / tot : ssig(yv);
      out[(size_t)(rowg + row_) * 4096 + u * 32 + j] = outv;
    }
    __syncthreads();   // single barrier per iteration
  }
  // epilogue: softmax + out for s = 127 (ys[1], written at iter 128)
  if (tid < 512) {
    int row_ = tid >> 5, j = tid & 31;
    float yv = ys[1][row_][j];
    float m = (j < 31) ? yv : -1e30f;
#pragma unroll
    for (int off = 16; off; off >>= 1) m = fmaxf(m, __shfl_xor(m, off, 32));
    float es = (j < 31) ? __expf(yv - m) : 0.f;
    float tot = es;
#pragma unroll
    for (int off = 16; off; off >>= 1) tot += __shfl_xor(tot, off, 32);
    float outv = (j < 31) ? es / tot : ssig(yv);
    out[(size_t)(rowg + row_) * 4096 + 127 * 32 + j] = outv;
  }
}

// ---------------------------------------------------------------------------
extern "C" void kernel_launch(void* const* d_in, const int* in_sizes, int n_in,
                              void* d_out, int out_size, void* d_ws, size_t ws_size,
                              hipStream_t stream) {
  (void)in_sizes; (void)n_in; (void)out_size; (void)ws_size;
  const float* x    = (const float*)d_in[0];
  const float* W1   = (const float*)d_in[1];
  const float* b1   = (const float*)d_in[2];
  const float* W2   = (const float*)d_in[3];
  const float* b2   = (const float*)d_in[4];
  const float* W3   = (const float*)d_in[5];
  const float* b3   = (const float*)d_in[6];
  const float* Wh1  = (const float*)d_in[7];
  const float* bh1  = (const float*)d_in[8];
  const float* Wh2  = (const float*)d_in[9];
  const float* bh2  = (const float*)d_in[10];
  const float* Wc1  = (const float*)d_in[11];
  const float* bc1  = (const float*)d_in[12];
  const float* Wc2  = (const float*)d_in[13];
  const float* bc2  = (const float*)d_in[14];
  const float* Wx1  = (const float*)d_in[15];
  const float* bx1  = (const float*)d_in[16];
  const float* Wx2  = (const float*)d_in[17];
  const float* bx2  = (const float*)d_in[18];
  const float* rWih = (const float*)d_in[19];
  const float* rWhh = (const float*)d_in[20];
  const float* rbih = (const float*)d_in[21];
  const float* rbhh = (const float*)d_in[22];
  const float* pWih = (const float*)d_in[23];
  const float* pWhh = (const float*)d_in[24];
  const float* pbih = (const float*)d_in[25];
  const float* pbhh = (const float*)d_in[26];

  char* w = (char*)d_ws;
  auto alloc = [&](size_t bytes) -> char* {
    char* p = w;
    w += (bytes + 255) & ~(size_t)255;
    return p;
  };
  u16* Xbf  = (u16*)alloc(1024 * 128 * 2);
  u16* T1   = (u16*)alloc(1024 * 512 * 2);
  u16* T2   = (u16*)alloc(1024 * 512 * 2);
  u16* T3   = (u16*)alloc(1024 * 512 * 2);
  u16* THCX = (u16*)alloc(1024 * 1536 * 2);  // fused TH|TC|TX
  u16* X0H  = (u16*)alloc(1024 * 512 * 2);   // cols 0..255 = x0, 256..511 = h
  float* CB = (float*)alloc(1024 * 256 * 4);
  u16* OUTS0= (u16*)alloc(1024 * 256 * 2);   // h_0 only
  u16* W1b  = (u16*)alloc(512 * 128 * 2);
  u16* W2b  = (u16*)alloc(512 * 512 * 2);
  u16* W3b  = (u16*)alloc(512 * 512 * 2);
  u16* WH123= (u16*)alloc(3 * 512 * 512 * 2);  // stacked Wh1b|Wc1b|Wx1b
  u16* Wh2b = (u16*)alloc(256 * 512 * 2);
  u16* Wc2b = (u16*)alloc(256 * 512 * 2);
  u16* Wx2b = (u16*)alloc(256 * 512 * 2);
  u16* WcatR= (u16*)alloc(1024 * 512 * 2);
  u8*  WsS  = (u8*)alloc(262144);
  u8*  pWsS = (u8*)alloc(32768);
  u8*  pWhhS= (u8*)alloc(4096);
  float* rbR = (float*)alloc(1024 * 4);
  float* pbR = (float*)alloc(128 * 4);
  float* bH123 = (float*)alloc(1536 * 4);

  PrepArgs pa;
  pa.x = x; pa.W1 = W1; pa.W2 = W2; pa.W3 = W3; pa.Wh1 = Wh1; pa.Wc1 = Wc1; pa.Wx1 = Wx1;
  pa.Wh2 = Wh2; pa.Wc2 = Wc2; pa.Wx2 = Wx2;
  pa.rWih = rWih; pa.rWhh = rWhh; pa.rbih = rbih; pa.rbhh = rbhh;
  pa.pWih = pWih; pa.pWhh = pWhh; pa.pbih = pbih; pa.pbhh = pbhh;
  pa.bh1 = bh1; pa.bc1 = bc1; pa.bx1 = bx1;
  pa.Xbf = Xbf; pa.W1b = W1b; pa.W2b = W2b; pa.W3b = W3b;
  pa.Wh1b = WH123; pa.Wc1b = WH123 + 262144; pa.Wx1b = WH123 + 524288;
  pa.Wh2b = Wh2b; pa.Wc2b = Wc2b; pa.Wx2b = Wx2b;
  pa.WcatR = WcatR;
  pa.WsS = WsS; pa.pWsS = pWsS; pa.pWhhS = pWhhS;
  pa.rbR = rbR; pa.pbR = pbR; pa.bH123 = bH123;
  prep<<<dim3(32, 17), 256, 0, stream>>>(pa);

  // MLP trunk
  gemm_act<<<dim3(16, 8), 256, 0, stream>>>(Xbf, W1b, b1, T1, nullptr, 128, 128, 512, 0, 1);
  gemm_act<<<dim3(16, 8), 256, 0, stream>>>(T1, W2b, b2, T2, nullptr, 512, 512, 512, 0, 1);
  gemm_act<<<dim3(16, 8), 256, 0, stream>>>(T2, W3b, b3, T3, nullptr, 512, 512, 512, 0, 1);
  // fused head layer-1: N=1536 (Wh1|Wc1|Wx1 on T3), 384 blocks
  gemm_act<<<dim3(16, 24), 256, 0, stream>>>(T3, WH123, bH123, THCX, nullptr, 512, 512, 1536, 0, 1);
  // head layer-2 (strided slices of THCX)
  gemm_act<<<dim3(16, 4), 256, 0, stream>>>(THCX,        Wh2b, bh2, X0H, nullptr, 512, 1536, 512, 256, 0); // h
  gemm_act<<<dim3(16, 4), 256, 0, stream>>>(THCX + 512,  Wc2b, bc2, nullptr, CB,  512, 1536, 256, 0, 0);   // c
  gemm_act<<<dim3(16, 4), 256, 0, stream>>>(THCX + 1024, Wx2b, bx2, X0H, nullptr, 512, 1536, 512, 0, 0);   // x0

  // decode step 0 (K=512 concat, bf16), then 3-stage pipelined fp8 decode+pred
  decode_step<<<dim3(16, 8), 256, 0, stream>>>(X0H, WcatR, rbR, CB, OUTS0, 512);
  decode_pred<<<64, 1024, 0, stream>>>(WsS, rbR, CB, OUTS0, pWsS, pWhhS, pbR,
                                       (float*)d_out);
}

// Round 13
// 833.798 us; speedup vs baseline: 1.1668x; 1.1668x over previous
//
#include <hip/hip_runtime.h>
#include <hip/hip_fp8.h>

typedef unsigned short u16;
typedef unsigned char u8;
typedef __attribute__((ext_vector_type(8))) __bf16 bfrag;
typedef long long f8frag;
typedef __attribute__((ext_vector_type(4))) float f32x4;
typedef __attribute__((ext_vector_type(4))) unsigned int u32x4;

static __device__ __forceinline__ f32x4 MFMA(bfrag a, bfrag b, f32x4 c) {
  return __builtin_amdgcn_mfma_f32_16x16x32_bf16(a, b, c, 0, 0, 0);
}
static __device__ __forceinline__ f32x4 MFMA8(f8frag a, f8frag b, f32x4 c) {
  return __builtin_amdgcn_mfma_f32_16x16x32_fp8_fp8(a, b, c, 0, 0, 0);
}

// float -> bf16 (RNE)
static __device__ __forceinline__ u16 f2b(float f) {
  union { float f; unsigned u; } v; v.f = f;
  unsigned r = (v.u + 0x7fffu + ((v.u >> 16) & 1u)) >> 16;
  return (u16)r;
}
// float -> fp8 e4m3 (OCP)
static __device__ __forceinline__ u8 f2e4m3(float f) {
  return __hip_fp8_e4m3(f).__x;
}
static __device__ __forceinline__ float ssig(float x) { return 1.f / (1.f + __expf(-x)); }
static __device__ __forceinline__ float stanh(float x) { return 1.f - 2.f / (__expf(2.f * x) + 1.f); }

// ---------------------------------------------------------------------------
// prep. Decode gate-retile: MFMA col n = g16*64 + gate*16 + m15 <-> source
// row gate*256 + g16*16 + m15.
// Case 15: decode weights fp8, LANE-SWIZZLED CONTIGUOUS fragment layout
// (one 512 B block per (gate,kt) fragment; load addr = base + lane*8 ->
// single-segment coalesced — the R11 2.4x win), split into two buffers:
//   WifS [g16][gate(i,f)][kt][512]  -> streamed from L2 each step
//   WgoS [g16][gate(g,o)][kt][512]  -> staged once into LDS
// Cases 12/13: pred weights, same swizzle. Case 16: concat head-1 biases.
// ---------------------------------------------------------------------------
struct PrepArgs {
  const float *x, *W1, *W2, *W3, *Wh1, *Wc1, *Wx1, *Wh2, *Wc2, *Wx2;
  const float *rWih, *rWhh, *rbih, *rbhh, *pWih, *pWhh, *pbih, *pbhh;
  const float *bh1, *bc1, *bx1;
  u16 *Xbf, *W1b, *W2b, *W3b, *Wh1b, *Wc1b, *Wx1b, *Wh2b, *Wc2b, *Wx2b;
  u16 *WcatR;
  u8 *WifS, *WgoS, *pWsS, *pWhhS;
  float *rbR, *pbR, *bH123;
};

__global__ __launch_bounds__(256) void prep(PrepArgs p) {
  const int tid0 = blockIdx.x * 256 + threadIdx.x;
  const int stride = gridDim.x * 256;
  switch (blockIdx.y) {
    case 0: for (int i = tid0; i < 131072; i += stride) p.Xbf[i] = f2b(p.x[i]); break;
    case 1: for (int i = tid0; i < 65536;  i += stride) p.W1b[i] = f2b(p.W1[i]); break;
    case 2: for (int i = tid0; i < 262144; i += stride) p.W2b[i] = f2b(p.W2[i]); break;
    case 3: for (int i = tid0; i < 262144; i += stride) p.W3b[i] = f2b(p.W3[i]); break;
    case 4: for (int i = tid0; i < 262144; i += stride) p.Wh1b[i] = f2b(p.Wh1[i]); break;
    case 5: for (int i = tid0; i < 262144; i += stride) p.Wc1b[i] = f2b(p.Wc1[i]); break;
    case 6: for (int i = tid0; i < 262144; i += stride) p.Wx1b[i] = f2b(p.Wx1[i]); break;
    case 7: for (int i = tid0; i < 131072; i += stride) p.Wh2b[i] = f2b(p.Wh2[i]); break;
    case 8: for (int i = tid0; i < 131072; i += stride) p.Wc2b[i] = f2b(p.Wc2[i]); break;
    case 9: for (int i = tid0; i < 131072; i += stride) p.Wx2b[i] = f2b(p.Wx2[i]); break;
    case 10: // step-0 concat weights (bf16, gate-retiled)
      for (int i = tid0; i < 262144; i += stride) {
        int n = i >> 8, k = i & 255;
        int srow = (((n >> 4) & 3) << 8) + ((n >> 6) << 4) + (n & 15);
        p.WcatR[n * 512 + k] = f2b(p.rWih[srow * 256 + k]);
        p.WcatR[n * 512 + 256 + k] = f2b(p.rWhh[srow * 256 + k]);
      }
      break;
    case 11:
      for (int i = tid0; i < 1024; i += stride) {
        int srow = (((i >> 4) & 3) << 8) + ((i >> 6) << 4) + (i & 15);
        p.rbR[i] = p.rbih[srow] + p.rbhh[srow];
      }
      break;
    case 12: // pred x-weights fp8, swizzled-contiguous
      for (int i = tid0; i < 32768; i += stride) {
        int j = i & 7, lane = (i >> 3) & 63, kt = (i >> 9) & 7, w = i >> 12;
        int n = w * 16 + (lane & 15);
        int srow = ((n & 3) << 5) + (n >> 2);
        int k = kt * 32 + ((lane >> 4) & 3) * 8 + j;
        p.pWsS[i] = f2e4m3(p.pWih[srow * 256 + k]);
      }
      break;
    case 13: // pred h-weights fp8, swizzled-contiguous
      for (int i = tid0; i < 4096; i += stride) {
        int j = i & 7, lane = (i >> 3) & 63, w = i >> 9;
        int n = w * 16 + (lane & 15);
        int srow = ((n & 3) << 5) + (n >> 2);
        int k = ((lane >> 4) & 3) * 8 + j;
        p.pWhhS[i] = f2e4m3(p.pWhh[srow * 32 + k]);
      }
      break;
    case 14:
      for (int i = tid0; i < 128; i += stride) {
        int srow = ((i & 3) << 5) + (i >> 2);
        p.pbR[i] = p.pbih[srow] + p.pbhh[srow];
      }
      break;
    case 15: // decode combined weights fp8, split i,f (stream) / g,o (LDS)
      for (int i = tid0; i < 262144; i += stride) {
        int j = i & 7, lane = (i >> 3) & 63, kt = (i >> 9) & 7;
        int gate = (i >> 12) & 3, g16 = i >> 14;
        int srow = gate * 256 + g16 * 16 + (lane & 15);
        int k = kt * 32 + ((lane >> 4) & 3) * 8 + j;
        u8 v = f2e4m3(p.rWih[srow * 256 + k] + p.rWhh[srow * 256 + k]);
        int dsti = (g16 * 2 + (gate & 1)) * 4096 + (i & 4095);
        if (gate < 2) p.WifS[dsti] = v;
        else          p.WgoS[dsti] = v;
      }
      break;
    case 16: // concat head-1 biases
      for (int i = tid0; i < 1536; i += stride)
        p.bH123[i] = (i < 512) ? p.bh1[i] : (i < 1024) ? p.bc1[i - 512] : p.bx1[i - 1024];
      break;
  }
}

// ---------------------------------------------------------------------------
// gemm_act: Y[1024,N] = act(X[1024,K] @ W[N,K]^T + bias), bf16 in, fp32 acc.
// lda = row stride of X (supports strided slices of the fused THCX buffer).
// ---------------------------------------------------------------------------
__global__ __launch_bounds__(256) void gemm_act(
    const u16* __restrict__ X, const u16* __restrict__ W,
    const float* __restrict__ bias,
    u16* __restrict__ Yb, float* __restrict__ Yf,
    int K, int lda, int ldo, int coloff, int leaky) {
  const int rt = blockIdx.x, ct = blockIdx.y;
  const int lane = threadIdx.x & 63, wave = threadIdx.x >> 6;
  const int m15 = lane & 15, q = lane >> 4, kq = q * 8;
  const int row = rt * 64 + wave * 16 + m15;
  f32x4 acc[4] = {};
  const u16* xp = X + (size_t)row * lda + kq;
  for (int k0 = 0; k0 < K; k0 += 32) {
    bfrag a = *(const bfrag*)(xp + k0);
#pragma unroll
    for (int nt = 0; nt < 4; nt++) {
      const u16* wp = W + (size_t)(ct * 64 + nt * 16 + m15) * K + k0 + kq;
      acc[nt] = MFMA(a, *(const bfrag*)wp, acc[nt]);
    }
  }
#pragma unroll
  for (int nt = 0; nt < 4; nt++) {
    int col = ct * 64 + nt * 16 + m15;
    float bv = bias[col];
#pragma unroll
    for (int r = 0; r < 4; r++) {
      int orow = rt * 64 + wave * 16 + q * 4 + r;
      float v = acc[nt][r] + bv;
      if (leaky) v = v >= 0.f ? v : 0.2f * v;
      if (Yb) Yb[(size_t)orow * ldo + coloff + col] = f2b(v);
      else    Yf[(size_t)orow * ldo + coloff + col] = v;
    }
  }
}

// ---------------------------------------------------------------------------
// decode_step: step 0 only (K=512 concat input, bf16), gate-retiled columns.
// ---------------------------------------------------------------------------
__global__ __launch_bounds__(256) void decode_step(
    const u16* __restrict__ A, const u16* __restrict__ W,
    const float* __restrict__ rb,
    float* __restrict__ C, u16* __restrict__ Hout, int K) {
  __shared__ float g[64][128];
  const int rt = blockIdx.x, cg = blockIdx.y;
  const int lane = threadIdx.x & 63, wave = threadIdx.x >> 6;
  const int m15 = lane & 15, q = lane >> 4, kq = q * 8;
  const int row = rt * 64 + wave * 16 + m15;
  f32x4 acc[8] = {};
  const u16* ap = A + (size_t)row * K + kq;
  for (int k0 = 0; k0 < K; k0 += 32) {
    bfrag a = *(const bfrag*)(ap + k0);
#pragma unroll
    for (int nt = 0; nt < 8; nt++) {
      const u16* wp = W + (size_t)(cg * 128 + nt * 16 + m15) * K + k0 + kq;
      acc[nt] = MFMA(a, *(const bfrag*)wp, acc[nt]);
    }
  }
#pragma unroll
  for (int nt = 0; nt < 8; nt++)
#pragma unroll
    for (int r = 0; r < 4; r++)
      g[wave * 16 + q * 4 + r][nt * 16 + m15] = acc[nt][r];
  __syncthreads();
  for (int t = threadIdx.x; t < 2048; t += 256) {
    int rl = t >> 5, hc = t & 31;
    int grow = rt * 64 + rl, gcol = cg * 32 + hc;
    int base = ((hc >> 4) << 6) + (hc & 15);
    float gi = g[rl][base +  0] + rb[cg * 128 + base +  0];
    float gf = g[rl][base + 16] + rb[cg * 128 + base + 16];
    float gg = g[rl][base + 32] + rb[cg * 128 + base + 32];
    float go = g[rl][base + 48] + rb[cg * 128 + base + 48];
    size_t ci = (size_t)grow * 256 + gcol;
    float c = C[ci];
    float cn = ssig(gf) * c + ssig(gi) * stanh(gg);
    float hn = ssig(go) * stanh(cn);
    C[ci] = cn;
    Hout[ci] = f2b(hn);
  }
}

// ---------------------------------------------------------------------------
// decode_pred v8: R11 two-phase skeleton (proven 493 us; the R12 single-
// region merge regressed to 730 by re-serializing the load batches) with:
//   (a) gates g,o staged ONCE in LDS (swizzled fragment layout, ds_read_b64
//       at base+lane*8 = conflict-free) -> streamed bytes halve to
//       128 KB/step/CU through the ~64 B/cyc L1 path;
//   (b) softmax(s-1) moved to waves 8..15 in phase 2, parallel with pred(s)
//       on waves 0..7 (ys parities disjoint; next same-parity write is one
//       barrier away).
// 64 blocks x 1024 thr, 16 rows/block, ONE barrier per step.
// ---------------------------------------------------------------------------
__global__ __launch_bounds__(1024, 4) void decode_pred(
    const u8* __restrict__ WifS,    // [131072] swizzled fp8 gates i,f (stream)
    const u8* __restrict__ WgoS,    // [131072] swizzled fp8 gates g,o (->LDS)
    const float* __restrict__ rb,   // rbR [1024]
    const float* __restrict__ C0,   // CB  [1024][256] (c after step 0)
    const u16* __restrict__ H0,     // h_0 [1024][256] bf16
    const u8* __restrict__ pWsS,    // [32768] swizzled fp8 pred x-weights
    const u8* __restrict__ pWhhS,   // [4096] swizzled fp8 pred h-weights
    const float* __restrict__ pb,   // pbR [128]
    float* __restrict__ out) {      // [1024][128][32]
  __shared__ u8 wglo[16][8192];        // 128 KB g,o weights [g16][gate2*4096+kt*512+..]
  __shared__ u8 hbuf8[2][16][272];     // 8.5 KB fp8 h ping-pong
  __shared__ float gbuf[8][16][20];    // 10 KB pred transpose
  __shared__ u8 hp8[2][16][40];        // 1.25 KB pred hidden
  __shared__ float ys[2][16][36];      // 4.5 KB pred y double-buffer
  const int tid = threadIdx.x;
  const int w = tid >> 6, lane = tid & 63;
  const int m15 = lane & 15, q = lane >> 4;
  const int rowg = blockIdx.x * 16;
  const int hc = w * 16 + m15;

  // stage g,o weights into LDS (one-time, 131072 B, 16 B/thread/iter)
  for (int i = tid * 16; i < 131072; i += 16384)
    *(u32x4*)(&wglo[0][0] + i) = *(const u32x4*)(WgoS + i);
  // h_0 -> fp8
  {
    int r = tid >> 6, c = (tid & 63) * 4;
    const u16* src = H0 + (size_t)(rowg + r) * 256 + c;
    u8 b4[4];
#pragma unroll
    for (int j = 0; j < 4; j++) {
      union { float f; unsigned u; } v; v.u = (unsigned)src[j] << 16;
      b4[j] = f2e4m3(v.f);
    }
    *(unsigned*)(&hbuf8[0][r][c]) =
        (unsigned)b4[0] | ((unsigned)b4[1] << 8) | ((unsigned)b4[2] << 16) | ((unsigned)b4[3] << 24);
  }
  for (int i = tid; i < 2 * 16 * 40; i += 1024) (&hp8[0][0][0])[i] = 0;

  // decode per-lane state
  float cst[4];
#pragma unroll
  for (int r = 0; r < 4; r++)
    cst[r] = C0[(size_t)(rowg + q * 4 + r) * 256 + hc];
  const float rbv0 = rb[w * 64 +  0 + m15], rbv1 = rb[w * 64 + 16 + m15];
  const float rbv2 = rb[w * 64 + 32 + m15], rbv3 = rb[w * 64 + 48 + m15];
  const u8* wsb_if = WifS + (size_t)w * 8192 + lane * 8;  // streamed i,f base
  const u8* wlds   = &wglo[w][0] + lane * 8;              // LDS g,o base

  // pred constants (waves 0..7)
  const int hloc = lane >> 4, prow = lane & 15;
  const int pcol = w * 4 + hloc;
  const int pc = (w < 8) ? pcol : 0;
  const float pb0 = pb[pc * 4 + 0], pb1 = pb[pc * 4 + 1];
  const float pb2 = pb[pc * 4 + 2], pb3 = pb[pc * 4 + 3];
  const u8* pwsb = pWsS + (size_t)(w & 7) * 4096 + lane * 8;
  const u8* pwhb = pWhhS + (size_t)(w & 7) * 512 + lane * 8;
  float cp = 0.f;
  __syncthreads();

  for (int s = 0; s < 128; s++) {
    // ---------- phase 1: decode step s (all 16 waves) ----------
    if (s) {
      const u8* h8 = &hbuf8[(s - 1) & 1][0][0];
      // batch: streamed i,f first (longest latency), then LDS g,o, then A
      f8frag Wv0[8], Wv1[8], Wv2[8], Wv3[8];
#pragma unroll
      for (int kt = 0; kt < 8; kt++) {
        Wv0[kt] = *(const f8frag*)(wsb_if + kt * 512);           // gate i
        Wv1[kt] = *(const f8frag*)(wsb_if + 4096 + kt * 512);    // gate f
      }
#pragma unroll
      for (int kt = 0; kt < 8; kt++) {
        Wv2[kt] = *(const f8frag*)(wlds + kt * 512);             // gate g (LDS)
        Wv3[kt] = *(const f8frag*)(wlds + 4096 + kt * 512);      // gate o (LDS)
      }
      f8frag a8v[8];
#pragma unroll
      for (int kt = 0; kt < 8; kt++)
        a8v[kt] = *(const f8frag*)(h8 + m15 * 272 + kt * 32 + q * 8);
      f32x4 ai = {}, af_ = {}, ag = {}, ao = {};
#pragma unroll
      for (int kt = 0; kt < 8; kt++) {
        ai  = MFMA8(a8v[kt], Wv0[kt], ai);
        af_ = MFMA8(a8v[kt], Wv1[kt], af_);
        ag  = MFMA8(a8v[kt], Wv2[kt], ag);
        ao  = MFMA8(a8v[kt], Wv3[kt], ao);
      }
      u8* hw8 = &hbuf8[s & 1][0][0];
#pragma unroll
      for (int r = 0; r < 4; r++) {
        float gi = ai[r] + rbv0, gf = af_[r] + rbv1;
        float gg = ag[r] + rbv2, go = ao[r] + rbv3;
        float cn = ssig(gf) * cst[r] + ssig(gi) * stanh(gg);
        float hn = ssig(go) * stanh(cn);
        cst[r] = cn;
        hw8[(q * 4 + r) * 272 + hc] = f2e4m3(hn);
      }
    }
    __syncthreads();   // h_s ready; orders previous phase-2 writes too
    // ---------- phase 2: pred(s) on waves 0..7 | softmax(s-1) on 8..15 ----
    if (w < 8) {
      const u8* xr8 = &hbuf8[s & 1][0][0];
      f8frag pbv[8], pav[8];
#pragma unroll
      for (int kt = 0; kt < 8; kt++) pbv[kt] = *(const f8frag*)(pwsb + kt * 512);
      f8frag phw = *(const f8frag*)pwhb;
#pragma unroll
      for (int kt = 0; kt < 8; kt++)
        pav[kt] = *(const f8frag*)(xr8 + m15 * 272 + kt * 32 + q * 8);
      f8frag pah = *(const f8frag*)(&hp8[s & 1][m15][q * 8]);
      f32x4 pacc = {};
#pragma unroll
      for (int kt = 0; kt < 8; kt++) pacc = MFMA8(pav[kt], pbv[kt], pacc);
      pacc = MFMA8(pah, phw, pacc);
      *(f32x4*)&gbuf[w][m15][q * 4] = pacc;  // per-wave transpose, in-order DS
      float g0 = gbuf[w][hloc * 4 + 0][prow] + pb0;
      float g1 = gbuf[w][hloc * 4 + 1][prow] + pb1;
      float g2 = gbuf[w][hloc * 4 + 2][prow] + pb2;
      float g3 = gbuf[w][hloc * 4 + 3][prow] + pb3;
      float cn = ssig(g1) * cp + ssig(g0) * stanh(g2);
      float hn_p = ssig(g3) * stanh(cn);
      cp = cn;
      hp8[(s + 1) & 1][prow][pcol] = f2e4m3(hn_p);
      ys[s & 1][prow][pcol] = hn_p;
    } else if (s > 0) {
      const int t = s - 1;
      int row_ = (tid - 512) >> 5, j = tid & 31;
      float yv = ys[t & 1][row_][j];
      float m = (j < 31) ? yv : -1e30f;
#pragma unroll
      for (int off = 16; off; off >>= 1) m = fmaxf(m, __shfl_xor(m, off, 32));
      float es = (j < 31) ? __expf(yv - m) : 0.f;
      float tot = es;
#pragma unroll
      for (int off = 16; off; off >>= 1) tot += __shfl_xor(tot, off, 32);
      float outv = (j < 31) ? es / tot : ssig(yv);
      out[(size_t)(rowg + row_) * 4096 + t * 32 + j] = outv;
    }
  }
  __syncthreads();
  // epilogue: softmax + out for s = 127 (ys[1])
  if (tid < 512) {
    int row_ = tid >> 5, j = tid & 31;
    float yv = ys[1][row_][j];
    float m = (j < 31) ? yv : -1e30f;
#pragma unroll
    for (int off = 16; off; off >>= 1) m = fmaxf(m, __shfl_xor(m, off, 32));
    float es = (j < 31) ? __expf(yv - m) : 0.f;
    float tot = es;
#pragma unroll
    for (int off = 16; off; off >>= 1) tot += __shfl_xor(tot, off, 32);
    float outv = (j < 31) ? es / tot : ssig(yv);
    out[(size_t)(rowg + row_) * 4096 + 127 * 32 + j] = outv;
  }
}

// ---------------------------------------------------------------------------
extern "C" void kernel_launch(void* const* d_in, const int* in_sizes, int n_in,
                              void* d_out, int out_size, void* d_ws, size_t ws_size,
                              hipStream_t stream) {
  (void)in_sizes; (void)n_in; (void)out_size; (void)ws_size;
  const float* x    = (const float*)d_in[0];
  const float* W1   = (const float*)d_in[1];
  const float* b1   = (const float*)d_in[2];
  const float* W2   = (const float*)d_in[3];
  const float* b2   = (const float*)d_in[4];
  const float* W3   = (const float*)d_in[5];
  const float* b3   = (const float*)d_in[6];
  const float* Wh1  = (const float*)d_in[7];
  const float* bh1  = (const float*)d_in[8];
  const float* Wh2  = (const float*)d_in[9];
  const float* bh2  = (const float*)d_in[10];
  const float* Wc1  = (const float*)d_in[11];
  const float* bc1  = (const float*)d_in[12];
  const float* Wc2  = (const float*)d_in[13];
  const float* bc2  = (const float*)d_in[14];
  const float* Wx1  = (const float*)d_in[15];
  const float* bx1  = (const float*)d_in[16];
  const float* Wx2  = (const float*)d_in[17];
  const float* bx2  = (const float*)d_in[18];
  const float* rWih = (const float*)d_in[19];
  const float* rWhh = (const float*)d_in[20];
  const float* rbih = (const float*)d_in[21];
  const float* rbhh = (const float*)d_in[22];
  const float* pWih = (const float*)d_in[23];
  const float* pWhh = (const float*)d_in[24];
  const float* pbih = (const float*)d_in[25];
  const float* pbhh = (const float*)d_in[26];

  char* w = (char*)d_ws;
  auto alloc = [&](size_t bytes) -> char* {
    char* p = w;
    w += (bytes + 255) & ~(size_t)255;
    return p;
  };
  u16* Xbf  = (u16*)alloc(1024 * 128 * 2);
  u16* T1   = (u16*)alloc(1024 * 512 * 2);
  u16* T2   = (u16*)alloc(1024 * 512 * 2);
  u16* T3   = (u16*)alloc(1024 * 512 * 2);
  u16* THCX = (u16*)alloc(1024 * 1536 * 2);  // fused TH|TC|TX
  u16* X0H  = (u16*)alloc(1024 * 512 * 2);   // cols 0..255 = x0, 256..511 = h
  float* CB = (float*)alloc(1024 * 256 * 4);
  u16* OUTS0= (u16*)alloc(1024 * 256 * 2);   // h_0 only
  u16* W1b  = (u16*)alloc(512 * 128 * 2);
  u16* W2b  = (u16*)alloc(512 * 512 * 2);
  u16* W3b  = (u16*)alloc(512 * 512 * 2);
  u16* WH123= (u16*)alloc(3 * 512 * 512 * 2);  // stacked Wh1b|Wc1b|Wx1b
  u16* Wh2b = (u16*)alloc(256 * 512 * 2);
  u16* Wc2b = (u16*)alloc(256 * 512 * 2);
  u16* Wx2b = (u16*)alloc(256 * 512 * 2);
  u16* WcatR= (u16*)alloc(1024 * 512 * 2);
  u8*  WifS = (u8*)alloc(131072);
  u8*  WgoS = (u8*)alloc(131072);
  u8*  pWsS = (u8*)alloc(32768);
  u8*  pWhhS= (u8*)alloc(4096);
  float* rbR = (float*)alloc(1024 * 4);
  float* pbR = (float*)alloc(128 * 4);
  float* bH123 = (float*)alloc(1536 * 4);

  PrepArgs pa;
  pa.x = x; pa.W1 = W1; pa.W2 = W2; pa.W3 = W3; pa.Wh1 = Wh1; pa.Wc1 = Wc1; pa.Wx1 = Wx1;
  pa.Wh2 = Wh2; pa.Wc2 = Wc2; pa.Wx2 = Wx2;
  pa.rWih = rWih; pa.rWhh = rWhh; pa.rbih = rbih; pa.rbhh = rbhh;
  pa.pWih = pWih; pa.pWhh = pWhh; pa.pbih = pbih; pa.pbhh = pbhh;
  pa.bh1 = bh1; pa.bc1 = bc1; pa.bx1 = bx1;
  pa.Xbf = Xbf; pa.W1b = W1b; pa.W2b = W2b; pa.W3b = W3b;
  pa.Wh1b = WH123; pa.Wc1b = WH123 + 262144; pa.Wx1b = WH123 + 524288;
  pa.Wh2b = Wh2b; pa.Wc2b = Wc2b; pa.Wx2b = Wx2b;
  pa.WcatR = WcatR;
  pa.WifS = WifS; pa.WgoS = WgoS; pa.pWsS = pWsS; pa.pWhhS = pWhhS;
  pa.rbR = rbR; pa.pbR = pbR; pa.bH123 = bH123;
  prep<<<dim3(32, 17), 256, 0, stream>>>(pa);

  // MLP trunk
  gemm_act<<<dim3(16, 8), 256, 0, stream>>>(Xbf, W1b, b1, T1, nullptr, 128, 128, 512, 0, 1);
  gemm_act<<<dim3(16, 8), 256, 0, stream>>>(T1, W2b, b2, T2, nullptr, 512, 512, 512, 0, 1);
  gemm_act<<<dim3(16, 8), 256, 0, stream>>>(T2, W3b, b3, T3, nullptr, 512, 512, 512, 0, 1);
  // fused head layer-1: N=1536 (Wh1|Wc1|Wx1 on T3), 384 blocks
  gemm_act<<<dim3(16, 24), 256, 0, stream>>>(T3, WH123, bH123, THCX, nullptr, 512, 512, 1536, 0, 1);
  // head layer-2 (strided slices of THCX)
  gemm_act<<<dim3(16, 4), 256, 0, stream>>>(THCX,        Wh2b, bh2, X0H, nullptr, 512, 1536, 512, 256, 0); // h
  gemm_act<<<dim3(16, 4), 256, 0, stream>>>(THCX + 512,  Wc2b, bc2, nullptr, CB,  512, 1536, 256, 0, 0);   // c
  gemm_act<<<dim3(16, 4), 256, 0, stream>>>(THCX + 1024, Wx2b, bx2, X0H, nullptr, 512, 1536, 512, 0, 0);   // x0

  // decode step 0 (K=512 concat, bf16), then v8 two-phase fp8 decode+pred
  decode_step<<<dim3(16, 8), 256, 0, stream>>>(X0H, WcatR, rbR, CB, OUTS0, 512);
  decode_pred<<<64, 1024, 0, stream>>>(WifS, WgoS, rbR, CB, OUTS0, pWsS, pWhhS, pbR,
                                       (float*)d_out);
}